// Round 1
// baseline (377.193 us; speedup 1.0000x reference)
//
#include <hip/hip_runtime.h>
#include <math.h>

#define T_DIM 8192
#define D_DIM 7168
#define E_DIM 256
#define N_GROUPS 8
#define TOPK_GROUPS 4
#define TOP_K 8

#define N_TOK 64      // tokens per GEMM block
#define BK 64         // k per staging chunk (2 MFMA k-steps)
#define NCHUNK (D_DIM / BK)           // 112
#define CHUNK_HALVES (E_DIM * BK)     // 16384 halves = 32 KB image per chunk
#define WSCALE 512.0f
#define INV_WSCALE (1.0f / 512.0f)

typedef _Float16 half8 __attribute__((ext_vector_type(8)));
typedef _Float16 half4v __attribute__((ext_vector_type(4)));
typedef float floatx4 __attribute__((ext_vector_type(4)));

// global->LDS async DMA, 16B per lane. LDS dest must be wave-uniform base
// (linear, lane*16 appended by HW); swizzle lives in the SOURCE layout.
#define GLOAD_LDS16(gp, lp)                                                     \
    __builtin_amdgcn_global_load_lds(                                           \
        (const __attribute__((address_space(1))) void*)(gp),                    \
        (__attribute__((address_space(3))) void*)(lp), 16, 0, 0)

// ---------------------------------------------------------------------------
// Kernel 0: split W [D][E] fp32 -> wph/wpl, stored as per-chunk GEMM-ready
// swizzled LDS images: chunk c holds bytes [c*32768, +32768) where the half
// for (expert e, k = c*64 + g*8 + j) lives at halves-offset
//   e*64 + ((g ^ (e&7))<<3) + j
// i.e. exactly the As tile image the GEMM reads. This lets the GEMM stage A
// with pure global_load_lds (linear dest, pre-swizzled source — rule #21).
// ---------------------------------------------------------------------------
__global__ __launch_bounds__(256) void wprep_kernel(
    const float* __restrict__ w, _Float16* __restrict__ wph, _Float16* __restrict__ wpl)
{
    __shared__ float tile[64][65];
    const int c = blockIdx.x;                 // k-chunk index
    const int k0 = c * 64, e0 = blockIdx.y * 64;
    const int tid = threadIdx.x;
    {
        const int kk = tid >> 4, e4 = (tid & 15) * 4;
#pragma unroll
        for (int i = 0; i < 4; i++) {
            const float4 v = *(const float4*)(w + (size_t)(k0 + kk + i * 16) * E_DIM + e0 + e4);
            tile[kk + i * 16][e4 + 0] = v.x;
            tile[kk + i * 16][e4 + 1] = v.y;
            tile[kk + i * 16][e4 + 2] = v.z;
            tile[kk + i * 16][e4 + 3] = v.w;
        }
    }
    __syncthreads();
    {
        const int ee = tid >> 4, kk4 = (tid & 15) * 4;
        const int g = kk4 >> 3, j0 = kk4 & 7;   // granule, half-granule offset
#pragma unroll
        for (int i = 0; i < 4; i++) {
            const int el = ee + i * 16;
            const int e = e0 + el;
            half4v hh, ll;
#pragma unroll
            for (int j = 0; j < 4; j++) {
                const float v = tile[kk4 + j][el] * WSCALE;
                const _Float16 h = (_Float16)v;
                hh[j] = h;
                ll[j] = (_Float16)(v - (float)h);
            }
            const size_t off = (size_t)c * CHUNK_HALVES + (size_t)e * BK +
                               (((g ^ (e & 7)) << 3) + j0);
            *(half4v*)(wph + off) = hh;
            *(half4v*)(wpl + off) = ll;
        }
    }
}

// ---------------------------------------------------------------------------
// Kernel 1: split-fp16 MFMA GEMM. Block = all 256 experts x 64 tokens,
// K-split over gridDim.x. Writes raw z' = x.(512 W) partials (fp32).
// MFMA m = expert (A operand = W^T), n = token (B operand = x).
// A-tile staged via global_load_lds dwordx4 from the pre-swizzled wph/wpl
// images (no VGPR round-trip, no staging VALU). B loads are issued BEFORE
// the DMAs so the cvt's vmcnt wait leaves all 16 DMAs in flight.
// ---------------------------------------------------------------------------
__device__ __forceinline__ void cvt_split8(const float4 v0, const float4 v1,
                                           half8& h, half8& l)
{
    float f[8] = {v0.x, v0.y, v0.z, v0.w, v1.x, v1.y, v1.z, v1.w};
#pragma unroll
    for (int j = 0; j < 8; j++) {
        const _Float16 hh = (_Float16)f[j];
        h[j] = hh;
        l[j] = (_Float16)(f[j] - (float)hh);
    }
}

template <bool CONVW>
__global__ __launch_bounds__(256, 2) void gemm_split_kernel(
    const float* __restrict__ x, const _Float16* __restrict__ wph,
    const _Float16* __restrict__ wpl, const float* __restrict__ wraw,
    float* __restrict__ partial, int kslen)
{
    __shared__ _Float16 As[2][CHUNK_HALVES];   // [hi/lo][swizzled (e,k) image]
    __shared__ _Float16 Bs[2][N_TOK * BK];     // [hi/lo][swizzled (t,k)]

    const int s = blockIdx.x, m = blockIdx.y;
    const int tid = threadIdx.x;
    const int k0 = s * kslen;
    const size_t t0 = (size_t)m * N_TOK;

    const int wave = tid >> 6, lane = tid & 63;
    const int lm = lane & 15, kq = lane >> 4; // fragment row / k-granule
    const int we0 = wave * 64;                // wave's expert base (4 waves x 64e)

    floatx4 acc[4][4];
#pragma unroll
    for (int mt = 0; mt < 4; mt++)
#pragma unroll
        for (int nt = 0; nt < 4; nt++) acc[mt][nt] = (floatx4)0.0f;

    for (int kc = k0; kc < k0 + kslen; kc += BK) {
        // ---- issue B global loads first (oldest in vmcnt queue) ----
        const int bt = tid >> 3, bkq = tid & 7;
        float4 v0[2], v1[2];
#pragma unroll
        for (int i = 0; i < 2; i++) {
            const float* xp = x + (t0 + bt + i * 32) * (size_t)D_DIM + kc + bkq * 8;
            v0[i] = *(const float4*)(xp);
            v1[i] = *(const float4*)(xp + 4);
        }

        // ---- stage A: 32 KB hi + 32 KB lo via async DMA ----
        if (!CONVW) {
            const int c = kc >> 6;
            const size_t cb = (size_t)c * CHUNK_HALVES;
            const int so = wave * 8192 + lane * 16;     // byte offset in image
            const char* gh = (const char*)(wph + cb) + so;
            const char* gl = (const char*)(wpl + cb) + so;
            char* lh = (char*)&As[0][0] + wave * 8192;  // wave-uniform LDS base
            char* ll = (char*)&As[1][0] + wave * 8192;
#pragma unroll
            for (int i = 0; i < 8; i++) {
                GLOAD_LDS16(gh + i * 1024, lh + i * 1024);
                GLOAD_LDS16(gl + i * 1024, ll + i * 1024);
            }
        } else {
            // fallback: convert from raw w[k][e] (coalesced reads, scattered b16 writes)
#pragma unroll
            for (int i = 0; i < 16; i++) {
                const int f = tid + i * 256;
                const int kk = f >> 6;
                const int e4 = (f & 63) << 2;
                const float4 v = *(const float4*)(wraw + (size_t)(kc + kk) * E_DIM + e4);
                const float fv[4] = {v.x, v.y, v.z, v.w};
                const int kg = kk >> 3, ko = kk & 7;
#pragma unroll
                for (int j = 0; j < 4; j++) {
                    const int e = e4 + j;
                    const float sv = fv[j] * WSCALE;
                    const _Float16 hh = (_Float16)sv;
                    const int off = e * BK + ((kg ^ (e & 7)) << 3) + ko;
                    As[0][off] = hh;
                    As[1][off] = (_Float16)(sv - (float)hh);
                }
            }
        }

        // ---- B cvt + LDS write (waits only on the 4 B loads; DMAs in flight) ----
        {
#pragma unroll
            for (int i = 0; i < 2; i++) {
                const int t = bt + i * 32;
                half8 h, l;
                cvt_split8(v0[i], v1[i], h, l);
                const int off = t * BK + ((bkq ^ (t & 7)) << 3);
                *(half8*)&Bs[0][off] = h;
                *(half8*)&Bs[1][off] = l;
            }
        }
        __syncthreads();   // drains vmcnt(0): DMAs complete

        // ---- compute: 2 k-steps of 32 ----
#pragma unroll
        for (int ks = 0; ks < 2; ks++) {
            const int kqg = ks * 4 + kq; // granule 0..7
            half8 ah[4], al[4];
#pragma unroll
            for (int mt = 0; mt < 4; mt++) {
                const int e = we0 + mt * 16 + lm;
                const int off = e * BK + ((kqg ^ (e & 7)) << 3);
                ah[mt] = *(const half8*)&As[0][off];
                al[mt] = *(const half8*)&As[1][off];
            }
#pragma unroll
            for (int nt = 0; nt < 4; nt++) {
                const int t = nt * 16 + lm;
                const int off = t * BK + ((kqg ^ (t & 7)) << 3);
                const half8 bh = *(const half8*)&Bs[0][off];
                const half8 bl = *(const half8*)&Bs[1][off];
#pragma unroll
                for (int mt = 0; mt < 4; mt++) {
                    acc[mt][nt] = __builtin_amdgcn_mfma_f32_16x16x32_f16(ah[mt], bh, acc[mt][nt], 0, 0, 0);
                    acc[mt][nt] = __builtin_amdgcn_mfma_f32_16x16x32_f16(ah[mt], bl, acc[mt][nt], 0, 0, 0);
                    acc[mt][nt] = __builtin_amdgcn_mfma_f32_16x16x32_f16(al[mt], bh, acc[mt][nt], 0, 0, 0);
                }
            }
        }
        __syncthreads();
    }

    // ---- epilogue: store raw z' partials. C/D: col(token)=lane&15, row(e)=(lane>>4)*4+r
    float* pout = partial + (size_t)s * T_DIM * E_DIM;
    const int rq = lane >> 4;
#pragma unroll
    for (int nt = 0; nt < 4; nt++) {
        const size_t t = t0 + nt * 16 + lm;
#pragma unroll
        for (int mt = 0; mt < 4; mt++) {
            const int e = we0 + mt * 16 + rq * 4;
            *(floatx4*)(pout + t * E_DIM + e) = acc[mt][nt];
        }
    }
}

// ---------------------------------------------------------------------------
// Kernel 2: per-token routing. One wave per token, no barriers.
// Sums KS partials, z = sum * (1/512), score = sigmoid(z).
// ---------------------------------------------------------------------------
__global__ __launch_bounds__(64) void router_kernel(
    const float* __restrict__ partial, const float* __restrict__ bias,
    float* __restrict__ w_out, float* __restrict__ i_out, int ks)
{
    const int t = blockIdx.x;
    const int lane = threadIdx.x;

    __shared__ float sraw[E_DIM];

    float4 zv = make_float4(0.f, 0.f, 0.f, 0.f);
    for (int s = 0; s < ks; s++) {
        const float4 p = *(const float4*)(partial + (size_t)s * T_DIM * E_DIM +
                                          (size_t)t * E_DIM + lane * 4);
        zv.x += p.x; zv.y += p.y; zv.z += p.z; zv.w += p.w;
    }
    float4 sv;
    sv.x = 1.0f / (1.0f + expf(-zv.x * INV_WSCALE));
    sv.y = 1.0f / (1.0f + expf(-zv.y * INV_WSCALE));
    sv.z = 1.0f / (1.0f + expf(-zv.z * INV_WSCALE));
    sv.w = 1.0f / (1.0f + expf(-zv.w * INV_WSCALE));

    const float4 bz = *(const float4*)(bias + lane * 4);
    *(float4*)(&sraw[lane * 4]) = sv; // single wave: no barrier needed

    float sb[4];
    sb[0] = sv.x + bz.x; sb[1] = sv.y + bz.y; sb[2] = sv.z + bz.z; sb[3] = sv.w + bz.w;

    // group top-2 sum (8 lanes per group)
    float m1 = -INFINITY, m2 = -INFINITY;
#pragma unroll
    for (int j = 0; j < 4; j++) {
        const float v = sb[j];
        if (v > m1) { m2 = m1; m1 = v; }
        else if (v > m2) { m2 = v; }
    }
#pragma unroll
    for (int d = 1; d < 8; d <<= 1) {
        const float o1 = __shfl_xor(m1, d);
        const float o2 = __shfl_xor(m2, d);
        const float hi = fmaxf(m1, o1);
        const float lo = fminf(m1, o1);
        m2 = fmaxf(lo, fmaxf(m2, o2));
        m1 = hi;
    }
    const float gscore = m1 + m2;

    float gs[N_GROUPS];
#pragma unroll
    for (int g = 0; g < N_GROUPS; g++) gs[g] = __shfl(gscore, g * 8);

    unsigned gmask = 0u;
#pragma unroll
    for (int r = 0; r < TOPK_GROUPS; r++) {
        int best = 0; float bv = -INFINITY;
#pragma unroll
        for (int g = 0; g < N_GROUPS; g++) {
            const bool taken = (gmask >> g) & 1u;
            if (!taken && gs[g] > bv) { bv = gs[g]; best = g; }
        }
        gmask |= (1u << best);
    }

    const int myg = lane >> 3;
    const float keep = ((gmask >> myg) & 1u) ? 1.0f : 0.0f;
    float v[4];
#pragma unroll
    for (int j = 0; j < 4; j++) v[j] = keep * sb[j];

    int selIdx[TOP_K];
#pragma unroll
    for (int it = 0; it < TOP_K; it++) {
        float bv = -INFINITY; int bi = E_DIM;
#pragma unroll
        for (int j = 0; j < 4; j++) {
            if (v[j] > bv) { bv = v[j]; bi = 4 * lane + j; }
        }
#pragma unroll
        for (int off = 32; off > 0; off >>= 1) {
            const float ov = __shfl_down(bv, off);
            const int   oi = __shfl_down(bi, off);
            if (ov > bv || (ov == bv && oi < bi)) { bv = ov; bi = oi; }
        }
        bi = __shfl(bi, 0);
        selIdx[it] = bi;
        if (lane == (bi >> 2)) v[bi & 3] = -INFINITY;
    }

    float wv[TOP_K];
    float wsum = 0.0f;
#pragma unroll
    for (int it = 0; it < TOP_K; it++) {
        wv[it] = sraw[selIdx[it]];
        wsum += wv[it];
    }
    const float inv = 2.5f / (wsum + 1e-20f);

#pragma unroll
    for (int it = 0; it < TOP_K; it++) {
        if (lane == it) {
            w_out[(size_t)t * TOP_K + it] = wv[it] * inv;
            i_out[(size_t)t * TOP_K + it] = (float)selIdx[it];
        }
    }
}

// ---------------------------------------------------------------------------
extern "C" void kernel_launch(void* const* d_in, const int* in_sizes, int n_in,
                              void* d_out, int out_size, void* d_ws, size_t ws_size,
                              hipStream_t stream) {
    const float* x    = (const float*)d_in[0];
    const float* w    = (const float*)d_in[1];
    const float* bias = (const float*)d_in[2];

    float* w_out = (float*)d_out;
    float* i_out = w_out + (size_t)T_DIM * TOP_K;

    const size_t PART = (size_t)T_DIM * E_DIM * sizeof(float); // 8.39 MB
    const size_t WT   = (size_t)E_DIM * D_DIM * sizeof(_Float16); // 3.67 MB

    int KS; bool convw;
    if      (ws_size >= 4 * PART + 2 * WT) { KS = 4; convw = false; }
    else if (ws_size >= 2 * PART + 2 * WT) { KS = 2; convw = false; }
    else if (ws_size >= 1 * PART + 2 * WT) { KS = 1; convw = false; }
    else                                   { KS = 1; convw = true;  }

    float* partial = (float*)d_ws;
    _Float16* wph = (_Float16*)((char*)d_ws + (size_t)KS * PART);
    _Float16* wpl = wph + (size_t)E_DIM * D_DIM;

    const int kslen = D_DIM / KS;

    if (!convw) {
        wprep_kernel<<<dim3(NCHUNK, E_DIM / 64), 256, 0, stream>>>(w, wph, wpl);
        gemm_split_kernel<false><<<dim3(KS, T_DIM / N_TOK), 256, 0, stream>>>(
            x, wph, wpl, w, partial, kslen);
    } else {
        gemm_split_kernel<true><<<dim3(KS, T_DIM / N_TOK), 256, 0, stream>>>(
            x, wph, wpl, w, partial, kslen);
    }
    router_kernel<<<T_DIM, 64, 0, stream>>>(partial, bias, w_out, i_out, KS);
}